// Round 7
// baseline (3853.808 us; speedup 1.0000x reference)
//
#include <hip/hip_runtime.h>
#include <hip/hip_bf16.h>

// RNN1DGeneral, swapped-MFMA + 2 batch-groups per block (TLP):
//   8 blocks x 32 batches (2 independent groups of 16), 512 threads = 8 waves.
//   Waves 0-3 -> group 0, waves 4-7 -> group 1: 2 waves/SIMD so the two
//   groups' phases overlap (LDS pipe stays busy during MFMA/VALU and v.v.).
//   Per group: wave w owns output cols [32w,32w+32) of BOTH layers.
//   MFMA computes D[col][batch] = W^T . h : A = W (static regs), B = h
//   (swizzled ds_read_b128; swizzle = full 4-bit batch XOR on 16B granules).
//   C layout: batch = lane&15, cols consecutive -> h writes are aligned
//   ds_write_b64. Logit via one MFMA/wave reusing B1v[w]. One barrier/step.

#define L_LEN 4096
#define HID   128
#define TPB   512
#define WPITCH 129

typedef float f32x4 __attribute__((ext_vector_type(4)));
typedef short s16x8 __attribute__((ext_vector_type(8)));
typedef short s16x4 __attribute__((ext_vector_type(4)));

__device__ __forceinline__ float eluf(float v) { return v > 0.f ? v : (__expf(v) - 1.f); }
__device__ __forceinline__ unsigned short f2bf(float v) {
    union { __hip_bfloat16 b; unsigned short u; } cv;
    cv.b = __float2bfloat16(v);
    return cv.u;
}

__global__ __launch_bounds__(TPB, 1)
void rnn_g2_kernel(const int*   __restrict__ x,
                   const float* __restrict__ W_in,
                   const float* __restrict__ W_c,
                   const float* __restrict__ W_out,
                   const float* __restrict__ b_out,
                   float* __restrict__ out)
{
    __shared__ __align__(16) unsigned short hAf[2][2][2][16][HID]; // [grp][q][layer][b][k] 32KB
    __shared__ unsigned xbsm[32 * WPITCH];                         // 16.5KB bitwords
    __shared__ float gbuf[2][2][4][16];                            // [q][grp][wave][batch]

    const int T  = threadIdx.x;
    const int w8 = T >> 6;        // 0..7
    const int wg = T >> 8;        // group 0/1
    const int w  = w8 & 3;        // wave-in-group: cols [32w, 32w+32)
    const int l  = T & 63, c = l & 15, g = l >> 4;
    const int grpT = T & 255;
    const int bb0 = blockIdx.x * 32;
    const int swz = c << 3;       // full 4-bit batch XOR, 16B granules

    // ---- pack x bits via ballot (coalesced) ----
    for (int idx = w8; idx < 32 * (L_LEN / 64); idx += 8) {
        int batch = idx >> 6;
        int pos   = ((idx & 63) << 6) + l;
        int v     = x[(bb0 + batch) * L_LEN + pos];
        unsigned long long mask = __ballot(v & 1);
        if (l == 0)  xbsm[batch * WPITCH + ((idx & 63) << 1)]     = (unsigned)mask;
        if (l == 32) xbsm[batch * WPITCH + ((idx & 63) << 1) + 1] = (unsigned)(mask >> 32);
    }
    for (int i = T; i < 2 * 2 * 2 * 16 * HID; i += TPB) ((unsigned short*)hAf)[i] = 0;

    // ---- static A fragments (W): lane holds A[row=c][k=kt*32+g*8+j] ----
    s16x8 Af[2][2][4];
    #pragma unroll
    for (int layer = 0; layer < 2; ++layer)
      #pragma unroll
      for (int mt = 0; mt < 2; ++mt) {
        const int col = w * 32 + mt * 16 + c;
        #pragma unroll
        for (int kt = 0; kt < 4; ++kt) {
            s16x8 f;
            #pragma unroll
            for (int j = 0; j < 8; ++j)
                f[j] = (short)f2bf(W_c[(layer * HID + kt * 32 + g * 8 + j) * HID + col]);
            Af[layer][mt][kt] = f;
        }
      }
    s16x8 woA;
    #pragma unroll
    for (int j = 0; j < 8; ++j)
        woA[j] = (c == 0) ? (short)f2bf(W_out[w * 32 + g * 8 + j]) : (short)0;

    float R0v[2][4], R1v[2][4];
    #pragma unroll
    for (int mt = 0; mt < 2; ++mt)
      #pragma unroll
      for (int r = 0; r < 4; ++r) {
        int co = w * 32 + mt * 16 + 4 * g + r;
        R0v[mt][r] = eluf(W_in[co]);
        R1v[mt][r] = eluf(W_in[HID + co]);
      }
    const float b0 = b_out[0];

    const int ro0 = (0 * 32 + g * 8) ^ swz, ro1 = (1 * 32 + g * 8) ^ swz;
    const int ro2 = (2 * 32 + g * 8) ^ swz, ro3 = (3 * 32 + g * 8) ^ swz;
    const int wo0 = (w * 32 + 0 * 16 + 4 * g) ^ swz;
    const int wo1 = (w * 32 + 1 * 16 + 4 * g) ^ swz;

    float acc = 0.f;
    unsigned xw = 0;

    __syncthreads();

#define STEP(T_, Q_) do {                                                     \
    const int t_ = (T_);                                                      \
    s16x8 B1v[4], B0v[4];                                                     \
    B1v[0] = *(const s16x8*)&hAf[wg][Q_][1][c][ro0];                          \
    B1v[1] = *(const s16x8*)&hAf[wg][Q_][1][c][ro1];                          \
    B1v[2] = *(const s16x8*)&hAf[wg][Q_][1][c][ro2];                          \
    B1v[3] = *(const s16x8*)&hAf[wg][Q_][1][c][ro3];                          \
    if (t_ < L_LEN) {                                                         \
        B0v[0] = *(const s16x8*)&hAf[wg][Q_][0][c][ro0];                      \
        B0v[1] = *(const s16x8*)&hAf[wg][Q_][0][c][ro1];                      \
        B0v[2] = *(const s16x8*)&hAf[wg][Q_][0][c][ro2];                      \
        B0v[3] = *(const s16x8*)&hAf[wg][Q_][0][c][ro3];                      \
        if (((t_ - 1) & 31) == 0)                                             \
            xw = xbsm[(wg * 16 + c) * WPITCH + ((t_ - 1) >> 5)];              \
    }                                                                         \
    {   /* logit MFMA for h1[t-1]: reuse B1v[w] */                            \
        s16x8 Bw = (w == 0) ? B1v[0] : (w == 1) ? B1v[1]                      \
                 : (w == 2) ? B1v[2] : B1v[3];                                \
        f32x4 Cg = {0.f, 0.f, 0.f, 0.f};                                      \
        Cg = __builtin_amdgcn_mfma_f32_16x16x32_bf16(woA, Bw, Cg, 0, 0, 0);   \
        if (g == 0) gbuf[Q_][wg][w][c] = Cg[0];                               \
    }                                                                         \
    if (t_ > 1 && grpT < 16) {   /* consume step s = t-2 */                   \
        int s = t_ - 2;                                                       \
        float gg = gbuf[Q_ ^ 1][wg][0][grpT] + gbuf[Q_ ^ 1][wg][1][grpT]      \
                 + gbuf[Q_ ^ 1][wg][2][grpT] + gbuf[Q_ ^ 1][wg][3][grpT] + b0;\
        unsigned cw = xbsm[(wg * 16 + grpT) * WPITCH + (s >> 5)];             \
        int bit = (cw >> (s & 31)) & 1;                                       \
        float mm  = fmaxf(gg, 0.f);                                           \
        float lse = mm + __logf(__expf(gg - mm) + __expf(-mm));               \
        acc += 0.5f * ((bit ? gg : 0.f) - lse);                               \
    }                                                                         \
    if (t_ < L_LEN) {                                                         \
        f32x4 C0v[2], C1v[2];                                                 \
        _Pragma("unroll")                                                     \
        for (int mt = 0; mt < 2; ++mt) {                                      \
            f32x4 c0 = {0.f, 0.f, 0.f, 0.f};                                  \
            f32x4 c1 = {0.f, 0.f, 0.f, 0.f};                                  \
            _Pragma("unroll")                                                 \
            for (int kt = 0; kt < 4; ++kt) {                                  \
                c0 = __builtin_amdgcn_mfma_f32_16x16x32_bf16(                 \
                        Af[0][mt][kt], B0v[kt], c0, 0, 0, 0);                 \
                c1 = __builtin_amdgcn_mfma_f32_16x16x32_bf16(                 \
                        Af[1][mt][kt], B1v[kt], c1, 0, 0, 0);                 \
            }                                                                 \
            C0v[mt] = c0; C1v[mt] = c1;                                       \
        }                                                                     \
        const int bit = (int)((xw >> ((t_ - 1) & 31)) & 1u);                  \
        _Pragma("unroll")                                                     \
        for (int mt = 0; mt < 2; ++mt) {                                      \
            s16x4 p0, p1;                                                     \
            _Pragma("unroll")                                                 \
            for (int r = 0; r < 4; ++r) {                                     \
                float h0 = eluf(C0v[mt][r]) + (bit ? R1v[mt][r] : R0v[mt][r]);\
                float h1 = eluf(C1v[mt][r]) + h0;                             \
                p0[r] = (short)f2bf(h0);                                      \
                p1[r] = (short)f2bf(h1);                                      \
            }                                                                 \
            const int wof = (mt == 0) ? wo0 : wo1;                            \
            *(s16x4*)&hAf[wg][Q_ ^ 1][0][c][wof] = p0;                        \
            *(s16x4*)&hAf[wg][Q_ ^ 1][1][c][wof] = p1;                        \
        }                                                                     \
    }                                                                         \
    __syncthreads();                                                          \
} while (0)

    for (int t = 1; t <= L_LEN; t += 2) {
        STEP(t, 1);
        STEP(t + 1, 0);
    }
#undef STEP

    // final: consume step s = L-1 (logit written at t = 4096, parity 0)
    if (grpT < 16) {
        float gg = gbuf[0][wg][0][grpT] + gbuf[0][wg][1][grpT]
                 + gbuf[0][wg][2][grpT] + gbuf[0][wg][3][grpT] + b0;
        unsigned cw = xbsm[(wg * 16 + grpT) * WPITCH + ((L_LEN - 1) >> 5)];
        int bit = (cw >> ((L_LEN - 1) & 31)) & 1;
        float mm  = fmaxf(gg, 0.f);
        float lse = mm + __logf(__expf(gg - mm) + __expf(-mm));
        acc += 0.5f * ((bit ? gg : 0.f) - lse);
        out[bb0 + wg * 16 + grpT] = acc;
    }
}

extern "C" void kernel_launch(void* const* d_in, const int* in_sizes, int n_in,
                              void* d_out, int out_size, void* d_ws, size_t ws_size,
                              hipStream_t stream)
{
    const int*   x     = (const int*)  d_in[0];
    const float* W_in  = (const float*)d_in[1];
    const float* W_c   = (const float*)d_in[2];
    const float* W_out = (const float*)d_in[3];
    const float* b_out = (const float*)d_in[4];
    float* out = (float*)d_out;

    rnn_g2_kernel<<<8, TPB, 0, stream>>>(x, W_in, W_c, W_out, b_out, out);
}

// Round 8
// 2755.789 us; speedup vs baseline: 1.3984x; 1.3984x over previous
//
#include <hip/hip_runtime.h>
#include <hip/hip_bf16.h>

// RNN1DGeneral, layer-split waves + TLP:
//   16 blocks x 16 batches, 512 threads = 8 waves (2/SIMD).
//   Waves 0-3: layer 0, wave wv owns cols [32wv,32wv+32).
//   Waves 4-7: layer 1, same col split. Each wave reads ONLY its layer's
//   h-state (4 swizzled ds_read_b128) -> per-CU LDS reads halved vs r7.
//   Step: [read B | logit MFMA (L1) | consumer (wave7) | 8 MFMA | L0: elu+R,
//   write h0_new] barrier [L1: read h0_new (b64), h1=elu(C)+h0, write] barrier.
//   MFMA D[col][batch]: A = W (static regs), B = h; C: batch=lane&15,
//   cols = 4g+r consecutive -> aligned ds_write_b64. Swizzle: batch XOR on
//   16B granules. Logit g[batch] via one MFMA per L1 wave (kt=wv slice).

#define L_LEN 4096
#define HID   128
#define NB    16
#define TPB   512
#define WPITCH 129

typedef float f32x4 __attribute__((ext_vector_type(4)));
typedef short s16x8 __attribute__((ext_vector_type(8)));
typedef short s16x4 __attribute__((ext_vector_type(4)));

__device__ __forceinline__ float eluf(float v) { return v > 0.f ? v : (__expf(v) - 1.f); }
__device__ __forceinline__ unsigned short f2bf(float v) {
    union { __hip_bfloat16 b; unsigned short u; } cv;
    cv.b = __float2bfloat16(v);
    return cv.u;
}
__device__ __forceinline__ float bf2f(unsigned short u) {
    union { float f; unsigned v; } cv;
    cv.v = ((unsigned)u) << 16;
    return cv.f;
}

__global__ __launch_bounds__(TPB, 1)
void rnn_ls_kernel(const int*   __restrict__ x,
                   const float* __restrict__ W_in,
                   const float* __restrict__ W_c,
                   const float* __restrict__ W_out,
                   const float* __restrict__ b_out,
                   float* __restrict__ out)
{
    __shared__ __align__(16) unsigned short hAf[2][2][NB][HID]; // [q][layer][b][k] 16KB
    __shared__ unsigned xbsm[NB * WPITCH];                      // 8.25KB bitwords
    __shared__ float gbuf[2][4][NB];                            // [q][ktslice][batch]

    const int T  = threadIdx.x;
    const int w8 = T >> 6;        // 0..7
    const int Lw = w8 >> 2;       // wave's layer: 0 or 1
    const int wv = w8 & 3;        // col owner within layer: [32wv, 32wv+32)
    const int l  = T & 63, c = l & 15, g = l >> 4;
    const int bb0 = blockIdx.x * NB;
    const int swz = c << 3;       // batch XOR on 16B granules

    // ---- pack x bits via ballot (coalesced) ----
    for (int idx = w8; idx < NB * (L_LEN / 64); idx += 8) {
        int batch = idx >> 6;
        int pos   = ((idx & 63) << 6) + l;
        int v     = x[(bb0 + batch) * L_LEN + pos];
        unsigned long long mask = __ballot(v & 1);
        if (l == 0)  xbsm[batch * WPITCH + ((idx & 63) << 1)]     = (unsigned)mask;
        if (l == 32) xbsm[batch * WPITCH + ((idx & 63) << 1) + 1] = (unsigned)(mask >> 32);
    }
    for (int i = T; i < 2 * 2 * NB * HID; i += TPB) ((unsigned short*)hAf)[i] = 0;

    // ---- static A fragments: ONLY this wave's layer ----
    s16x8 Af[2][4];
    #pragma unroll
    for (int mt = 0; mt < 2; ++mt) {
        const int col = wv * 32 + mt * 16 + c;
        #pragma unroll
        for (int kt = 0; kt < 4; ++kt) {
            s16x8 f;
            #pragma unroll
            for (int j = 0; j < 8; ++j)
                f[j] = (short)f2bf(W_c[(Lw * HID + kt * 32 + g * 8 + j) * HID + col]);
            Af[mt][kt] = f;
        }
    }
    s16x8 woA;
    #pragma unroll
    for (int j = 0; j < 8; ++j)
        woA[j] = (c == 0) ? (short)f2bf(W_out[wv * 32 + g * 8 + j]) : (short)0;

    float R0v[2][4], R1v[2][4];
    #pragma unroll
    for (int mt = 0; mt < 2; ++mt)
      #pragma unroll
      for (int r = 0; r < 4; ++r) {
        int co = wv * 32 + mt * 16 + 4 * g + r;
        R0v[mt][r] = eluf(W_in[co]);
        R1v[mt][r] = eluf(W_in[HID + co]);
      }
    const float b0 = b_out[0];

    const int ro0 = (g * 8) ^ swz,      ro1 = (32 + g * 8) ^ swz;
    const int ro2 = (64 + g * 8) ^ swz, ro3 = (96 + g * 8) ^ swz;
    const int wo0 = (wv * 32 + 4 * g) ^ swz;
    const int wo1 = (wv * 32 + 16 + 4 * g) ^ swz;

    float acc = 0.f;
    unsigned xw = 0;

    __syncthreads();

#define STEP(T_, Q_) do {                                                         \
    const int t_ = (T_);                                                          \
    s16x8 Bv0, Bv1, Bv2, Bv3;                                                     \
    if ((Lw == 1) || (t_ < L_LEN)) {                                              \
        Bv0 = *(const s16x8*)&hAf[Q_][Lw][c][ro0];                                \
        Bv1 = *(const s16x8*)&hAf[Q_][Lw][c][ro1];                                \
        Bv2 = *(const s16x8*)&hAf[Q_][Lw][c][ro2];                                \
        Bv3 = *(const s16x8*)&hAf[Q_][Lw][c][ro3];                                \
    }                                                                             \
    if (Lw == 1) {   /* logit MFMA for h1[t-1], k-slice kt = wv */                \
        s16x8 Bw = (wv == 0) ? Bv0 : (wv == 1) ? Bv1 : (wv == 2) ? Bv2 : Bv3;     \
        f32x4 Cg = {0.f, 0.f, 0.f, 0.f};                                          \
        Cg = __builtin_amdgcn_mfma_f32_16x16x32_bf16(woA, Bw, Cg, 0, 0, 0);       \
        if (g == 0) gbuf[Q_][wv][c] = Cg[0];                                      \
    }                                                                             \
    if (w8 == 7 && l < 16 && t_ > 1) {   /* consumer: step s = t-2 */             \
        int s_ = t_ - 2;                                                          \
        float gg = gbuf[Q_ ^ 1][0][c] + gbuf[Q_ ^ 1][1][c]                        \
                 + gbuf[Q_ ^ 1][2][c] + gbuf[Q_ ^ 1][3][c] + b0;                  \
        unsigned cw = xbsm[c * WPITCH + (s_ >> 5)];                               \
        int bit = (cw >> (s_ & 31)) & 1;                                          \
        float mm  = fmaxf(gg, 0.f);                                               \
        float lse = mm + __logf(__expf(gg - mm) + __expf(-mm));                   \
        acc += 0.5f * ((bit ? gg : 0.f) - lse);                                   \
    }                                                                             \
    f32x4 CA = {0.f, 0.f, 0.f, 0.f}, CB = {0.f, 0.f, 0.f, 0.f};                   \
    if (t_ < L_LEN) {                                                             \
        CA = __builtin_amdgcn_mfma_f32_16x16x32_bf16(Af[0][0], Bv0, CA, 0, 0, 0); \
        CA = __builtin_amdgcn_mfma_f32_16x16x32_bf16(Af[0][1], Bv1, CA, 0, 0, 0); \
        CA = __builtin_amdgcn_mfma_f32_16x16x32_bf16(Af[0][2], Bv2, CA, 0, 0, 0); \
        CA = __builtin_amdgcn_mfma_f32_16x16x32_bf16(Af[0][3], Bv3, CA, 0, 0, 0); \
        CB = __builtin_amdgcn_mfma_f32_16x16x32_bf16(Af[1][0], Bv0, CB, 0, 0, 0); \
        CB = __builtin_amdgcn_mfma_f32_16x16x32_bf16(Af[1][1], Bv1, CB, 0, 0, 0); \
        CB = __builtin_amdgcn_mfma_f32_16x16x32_bf16(Af[1][2], Bv2, CB, 0, 0, 0); \
        CB = __builtin_amdgcn_mfma_f32_16x16x32_bf16(Af[1][3], Bv3, CB, 0, 0, 0); \
        if (Lw == 0) {   /* h0_new = elu(.) + R[x[t-1]] ; write */                \
            if (((t_ - 1) & 31) == 0) xw = xbsm[c * WPITCH + ((t_ - 1) >> 5)];    \
            const int bit = (int)((xw >> ((t_ - 1) & 31)) & 1u);                  \
            s16x4 p0, p1;                                                         \
            _Pragma("unroll")                                                     \
            for (int r = 0; r < 4; ++r) {                                         \
                p0[r] = (short)f2bf(eluf(CA[r]) + (bit ? R1v[0][r] : R0v[0][r])); \
                p1[r] = (short)f2bf(eluf(CB[r]) + (bit ? R1v[1][r] : R0v[1][r])); \
            }                                                                     \
            *(s16x4*)&hAf[Q_ ^ 1][0][c][wo0] = p0;                                \
            *(s16x4*)&hAf[Q_ ^ 1][0][c][wo1] = p1;                                \
        }                                                                         \
    }                                                                             \
    __syncthreads();                                                              \
    if (Lw == 1 && t_ < L_LEN) {   /* h1_new = elu(.) + h0_new ; write */         \
        s16x4 h0a = *(const s16x4*)&hAf[Q_ ^ 1][0][c][wo0];                       \
        s16x4 h0b = *(const s16x4*)&hAf[Q_ ^ 1][0][c][wo1];                       \
        s16x4 p0, p1;                                                             \
        _Pragma("unroll")                                                         \
        for (int r = 0; r < 4; ++r) {                                             \
            p0[r] = (short)f2bf(eluf(CA[r]) + bf2f((unsigned short)h0a[r]));      \
            p1[r] = (short)f2bf(eluf(CB[r]) + bf2f((unsigned short)h0b[r]));      \
        }                                                                         \
        *(s16x4*)&hAf[Q_ ^ 1][1][c][wo0] = p0;                                    \
        *(s16x4*)&hAf[Q_ ^ 1][1][c][wo1] = p1;                                    \
    }                                                                             \
    __syncthreads();                                                              \
} while (0)

    for (int t = 1; t <= L_LEN; t += 2) {
        STEP(t, 1);
        STEP(t + 1, 0);
    }
#undef STEP

    // final: consume step s = L-1 (logit written at t = 4096, parity 0)
    if (w8 == 7 && l < 16) {
        float gg = gbuf[0][0][c] + gbuf[0][1][c] + gbuf[0][2][c] + gbuf[0][3][c] + b0;
        unsigned cw = xbsm[c * WPITCH + ((L_LEN - 1) >> 5)];
        int bit = (cw >> ((L_LEN - 1) & 31)) & 1;
        float mm  = fmaxf(gg, 0.f);
        float lse = mm + __logf(__expf(gg - mm) + __expf(-mm));
        acc += 0.5f * ((bit ? gg : 0.f) - lse);
        out[bb0 + c] = acc;
    }
}

extern "C" void kernel_launch(void* const* d_in, const int* in_sizes, int n_in,
                              void* d_out, int out_size, void* d_ws, size_t ws_size,
                              hipStream_t stream)
{
    const int*   x     = (const int*)  d_in[0];
    const float* W_in  = (const float*)d_in[1];
    const float* W_c   = (const float*)d_in[2];
    const float* W_out = (const float*)d_in[3];
    const float* b_out = (const float*)d_in[4];
    float* out = (float*)d_out;

    rnn_ls_kernel<<<16, TPB, 0, stream>>>(x, W_in, W_c, W_out, b_out, out);
}

// Round 9
// 2549.765 us; speedup vs baseline: 1.5114x; 1.0808x over previous
//
#include <hip/hip_runtime.h>
#include <hip/hip_bf16.h>

// RNN1DGeneral, layer-split + 1-step h1 lag => single barrier per step.
//   16 blocks x 16 batches, 512 threads = 8 waves (2/SIMD).
//   Waves 0-3 (L0): h0[t] = elu(h0[t-1]@W0) + R[x[t-1]]   (cols [32wv,+32))
//   Waves 4-7 (L1): h1[t-1] = elu(h1[t-2]@W1) + h0[t-1]   (lagged one iter)
//   All LDS reads hit parity q, all writes parity q^1 -> ONE barrier/step.
//   MFMA D[col][batch]: A = W (static regs), B = h (swizzled ds_read_b128).
//   C: batch=lane&15, cols consecutive -> aligned ds_write_b64 via
//   v_cvt_pk_bf16_f32 (2 f32 -> packed 2xbf16, 1 instr).
//   Logit for step s=t-2 via one MFMA per L1 wave on its loaded B-frags
//   (uniform if-chain select); 4-deep gbuf ring, consumer (wave7) at s=t-4.

#define L_LEN 4096
#define HID   128
#define NB    16
#define TPB   512
#define WPITCH 129

typedef float f32x4 __attribute__((ext_vector_type(4)));
typedef short s16x8 __attribute__((ext_vector_type(8)));

#define MFMA16(A_, B_, C_) __builtin_amdgcn_mfma_f32_16x16x32_bf16((A_), (B_), (C_), 0, 0, 0)

__device__ __forceinline__ float eluf(float v) { return v > 0.f ? v : (__expf(v) - 1.f); }
__device__ __forceinline__ unsigned cvtpk(float lo, float hi) {
    unsigned r;
    asm("v_cvt_pk_bf16_f32 %0, %1, %2" : "=v"(r) : "v"(lo), "v"(hi));
    return r;
}
__device__ __forceinline__ unsigned short f2bf(float v) {
    union { __hip_bfloat16 b; unsigned short u; } cv;
    cv.b = __float2bfloat16(v);
    return cv.u;
}

__global__ __launch_bounds__(TPB, 1)
void rnn_pipe_kernel(const int*   __restrict__ x,
                     const float* __restrict__ W_in,
                     const float* __restrict__ W_c,
                     const float* __restrict__ W_out,
                     const float* __restrict__ b_out,
                     float* __restrict__ out)
{
    __shared__ __align__(16) unsigned short hAf[2][2][NB][HID]; // [q][layer][b][k] 16KB
    __shared__ unsigned xbsm[NB * WPITCH];                      // 8.25KB bitwords
    __shared__ float gbuf[4][4][NB];                            // ring [t&3][ktslice][batch]

    const int T  = threadIdx.x;
    const int w8 = T >> 6;        // 0..7
    const int Lw = w8 >> 2;       // wave's layer
    const int wv = w8 & 3;        // col quarter [32wv, 32wv+32)
    const int l  = T & 63, c = l & 15, g = l >> 4;
    const int bb0 = blockIdx.x * NB;
    const int swz = c << 3;       // batch XOR on 16B granules

    // ---- pack x bits via ballot (coalesced) ----
    for (int idx = w8; idx < NB * (L_LEN / 64); idx += 8) {
        int batch = idx >> 6;
        int pos   = ((idx & 63) << 6) + l;
        int v     = x[(bb0 + batch) * L_LEN + pos];
        unsigned long long mask = __ballot(v & 1);
        if (l == 0)  xbsm[batch * WPITCH + ((idx & 63) << 1)]     = (unsigned)mask;
        if (l == 32) xbsm[batch * WPITCH + ((idx & 63) << 1) + 1] = (unsigned)(mask >> 32);
    }
    for (int i = T; i < 2 * 2 * NB * HID; i += TPB) ((unsigned short*)hAf)[i] = 0;

    // ---- static A fragments: this wave's layer only ----
    s16x8 Af[2][4];
    #pragma unroll
    for (int mt = 0; mt < 2; ++mt) {
        const int col = wv * 32 + mt * 16 + c;
        #pragma unroll
        for (int kt = 0; kt < 4; ++kt) {
            s16x8 f;
            #pragma unroll
            for (int j = 0; j < 8; ++j)
                f[j] = (short)f2bf(W_c[(Lw * HID + kt * 32 + g * 8 + j) * HID + col]);
            Af[mt][kt] = f;
        }
    }
    s16x8 woA;
    #pragma unroll
    for (int j = 0; j < 8; ++j)
        woA[j] = (c == 0) ? (short)f2bf(W_out[wv * 32 + g * 8 + j]) : (short)0;

    float R0v[2][4], R1v[2][4];
    #pragma unroll
    for (int mt = 0; mt < 2; ++mt)
      #pragma unroll
      for (int r = 0; r < 4; ++r) {
        int co = wv * 32 + mt * 16 + 4 * g + r;
        R0v[mt][r] = eluf(W_in[co]);
        R1v[mt][r] = eluf(W_in[HID + co]);
      }
    const float b0 = b_out[0];

    const int ro0 = (g * 8) ^ swz,      ro1 = (32 + g * 8) ^ swz;
    const int ro2 = (64 + g * 8) ^ swz, ro3 = (96 + g * 8) ^ swz;
    const int ro_w = (wv * 32 + g * 8) ^ swz;
    const int wo0 = (wv * 32 + 4 * g) ^ swz;
    const int wo1 = (wv * 32 + 16 + 4 * g) ^ swz;

    float acc = 0.f;
    unsigned xw = 0;

    __syncthreads();

#define STEP(T_, Q_) do {                                                         \
    const int t_ = (T_);                                                          \
    if (Lw == 0) {                                                                \
        if (t_ < L_LEN) {   /* h0[t] for t <= 4095 */                             \
            s16x8 B0 = *(const s16x8*)&hAf[Q_][0][c][ro0];                        \
            s16x8 B1 = *(const s16x8*)&hAf[Q_][0][c][ro1];                        \
            s16x8 B2 = *(const s16x8*)&hAf[Q_][0][c][ro2];                        \
            s16x8 B3 = *(const s16x8*)&hAf[Q_][0][c][ro3];                        \
            if (((t_ - 1) & 31) == 0) xw = xbsm[c * WPITCH + ((t_ - 1) >> 5)];    \
            f32x4 CA = {0.f,0.f,0.f,0.f}, CB = {0.f,0.f,0.f,0.f};                 \
            CA = MFMA16(Af[0][0], B0, CA); CA = MFMA16(Af[0][1], B1, CA);         \
            CA = MFMA16(Af[0][2], B2, CA); CA = MFMA16(Af[0][3], B3, CA);         \
            CB = MFMA16(Af[1][0], B0, CB); CB = MFMA16(Af[1][1], B1, CB);         \
            CB = MFMA16(Af[1][2], B2, CB); CB = MFMA16(Af[1][3], B3, CB);         \
            const int bit = (int)((xw >> ((t_ - 1) & 31)) & 1u);                  \
            float ha0 = eluf(CA[0]) + (bit ? R1v[0][0] : R0v[0][0]);              \
            float ha1 = eluf(CA[1]) + (bit ? R1v[0][1] : R0v[0][1]);              \
            float ha2 = eluf(CA[2]) + (bit ? R1v[0][2] : R0v[0][2]);              \
            float ha3 = eluf(CA[3]) + (bit ? R1v[0][3] : R0v[0][3]);              \
            float hb0 = eluf(CB[0]) + (bit ? R1v[1][0] : R0v[1][0]);              \
            float hb1 = eluf(CB[1]) + (bit ? R1v[1][1] : R0v[1][1]);              \
            float hb2 = eluf(CB[2]) + (bit ? R1v[1][2] : R0v[1][2]);              \
            float hb3 = eluf(CB[3]) + (bit ? R1v[1][3] : R0v[1][3]);              \
            uint2 pa, pb;                                                         \
            pa.x = cvtpk(ha0, ha1); pa.y = cvtpk(ha2, ha3);                       \
            pb.x = cvtpk(hb0, hb1); pb.y = cvtpk(hb2, hb3);                       \
            *(uint2*)&hAf[Q_ ^ 1][0][c][wo0] = pa;                                \
            *(uint2*)&hAf[Q_ ^ 1][0][c][wo1] = pb;                                \
        }                                                                         \
    } else {                                                                      \
        if (t_ >= 2 && t_ <= L_LEN) {   /* h1[t-1] */                             \
            s16x8 B0 = *(const s16x8*)&hAf[Q_][1][c][ro0];                        \
            s16x8 B1 = *(const s16x8*)&hAf[Q_][1][c][ro1];                        \
            s16x8 B2 = *(const s16x8*)&hAf[Q_][1][c][ro2];                        \
            s16x8 B3 = *(const s16x8*)&hAf[Q_][1][c][ro3];                        \
            uint2 a0 = *(const uint2*)&hAf[Q_][0][c][wo0];  /* h0[t-1] bf16 */    \
            uint2 a1 = *(const uint2*)&hAf[Q_][0][c][wo1];                        \
            s16x8 Bw = B0;                                                        \
            if (wv == 1) Bw = B1; else if (wv == 2) Bw = B2;                      \
            else if (wv == 3) Bw = B3;                                            \
            f32x4 Cg = {0.f,0.f,0.f,0.f};                                         \
            Cg = MFMA16(woA, Bw, Cg);   /* logits_{t-2} partial, kt = wv */       \
            if (g == 0) gbuf[t_ & 3][wv][c] = Cg[0];                              \
            f32x4 CA = {0.f,0.f,0.f,0.f}, CB = {0.f,0.f,0.f,0.f};                 \
            CA = MFMA16(Af[0][0], B0, CA); CA = MFMA16(Af[0][1], B1, CA);         \
            CA = MFMA16(Af[0][2], B2, CA); CA = MFMA16(Af[0][3], B3, CA);         \
            CB = MFMA16(Af[1][0], B0, CB); CB = MFMA16(Af[1][1], B1, CB);         \
            CB = MFMA16(Af[1][2], B2, CB); CB = MFMA16(Af[1][3], B3, CB);         \
            float ha0 = eluf(CA[0]) + __uint_as_float(a0.x << 16);                \
            float ha1 = eluf(CA[1]) + __uint_as_float(a0.x & 0xffff0000u);        \
            float ha2 = eluf(CA[2]) + __uint_as_float(a0.y << 16);                \
            float ha3 = eluf(CA[3]) + __uint_as_float(a0.y & 0xffff0000u);        \
            float hb0 = eluf(CB[0]) + __uint_as_float(a1.x << 16);                \
            float hb1 = eluf(CB[1]) + __uint_as_float(a1.x & 0xffff0000u);        \
            float hb2 = eluf(CB[2]) + __uint_as_float(a1.y << 16);                \
            float hb3 = eluf(CB[3]) + __uint_as_float(a1.y & 0xffff0000u);        \
            uint2 pa, pb;                                                         \
            pa.x = cvtpk(ha0, ha1); pa.y = cvtpk(ha2, ha3);                       \
            pb.x = cvtpk(hb0, hb1); pb.y = cvtpk(hb2, hb3);                       \
            *(uint2*)&hAf[Q_ ^ 1][1][c][wo0] = pa;                                \
            *(uint2*)&hAf[Q_ ^ 1][1][c][wo1] = pb;                                \
        } else if (t_ == L_LEN + 1) {   /* final logit: s = 4095 */               \
            s16x8 Bw = *(const s16x8*)&hAf[Q_][1][c][ro_w];                       \
            f32x4 Cg = {0.f,0.f,0.f,0.f};                                         \
            Cg = MFMA16(woA, Bw, Cg);                                             \
            if (g == 0) gbuf[t_ & 3][wv][c] = Cg[0];                              \
        }                                                                         \
        if (w8 == 7 && l < 16 && t_ >= 4 && t_ <= L_LEN + 3) {  /* s = t-4 */     \
            int s_ = t_ - 4;                                                      \
            const float* gp = &gbuf[(t_ - 2) & 3][0][0];                          \
            float gg = gp[0 * NB + c] + gp[1 * NB + c]                            \
                     + gp[2 * NB + c] + gp[3 * NB + c] + b0;                      \
            unsigned cw = xbsm[c * WPITCH + (s_ >> 5)];                           \
            int bit2 = (cw >> (s_ & 31)) & 1;                                     \
            float mm  = fmaxf(gg, 0.f);                                           \
            float lse = mm + __logf(__expf(gg - mm) + __expf(-mm));               \
            acc += 0.5f * ((bit2 ? gg : 0.f) - lse);                              \
        }                                                                         \
    }                                                                             \
    __syncthreads();                                                              \
} while (0)

    for (int t = 1; t <= L_LEN + 3; t += 2) {
        STEP(t, 1);
        STEP(t + 1, 0);
    }
#undef STEP

    if (w8 == 7 && l < 16) out[bb0 + c] = acc;
}

extern "C" void kernel_launch(void* const* d_in, const int* in_sizes, int n_in,
                              void* d_out, int out_size, void* d_ws, size_t ws_size,
                              hipStream_t stream)
{
    const int*   x     = (const int*)  d_in[0];
    const float* W_in  = (const float*)d_in[1];
    const float* W_c   = (const float*)d_in[2];
    const float* W_out = (const float*)d_in[3];
    const float* b_out = (const float*)d_in[4];
    float* out = (float*)d_out;

    rnn_pipe_kernel<<<16, TPB, 0, stream>>>(x, W_in, W_c, W_out, b_out, out);
}